// Round 3
// baseline (800.324 us; speedup 1.0000x reference)
//
#include <hip/hip_runtime.h>
#include <hip/hip_bf16.h>

#define D 64
#define RPB 128          // rows per bucket (row_local fits in 7 bits)
#define NBMAX 1024       // max buckets (needs n_nodes <= 131072 for 17-bit col)

// ===========================================================================
// support = x @ (W0+W1+W2)   [N,64]@[64,64]
// ===========================================================================
__global__ __launch_bounds__(256) void gemm_kernel(const float* __restrict__ x,
                                                   const float* __restrict__ w0,
                                                   const float* __restrict__ w1,
                                                   const float* __restrict__ w2,
                                                   float* __restrict__ support,
                                                   int n) {
    __shared__ float Ws[D * D];
    __shared__ float xs[4][D];

    for (int i = threadIdx.x; i < D * D; i += 256)
        Ws[i] = w0[i] + w1[i] + w2[i];
    __syncthreads();

    const int wid  = threadIdx.x >> 6;
    const int lane = threadIdx.x & 63;
    int row = blockIdx.x * 4 + wid;
    const int nw = gridDim.x * 4;

    for (; row < n; row += nw) {
        xs[wid][lane] = x[(size_t)row * D + lane];
        float acc = 0.0f;
#pragma unroll
        for (int k = 0; k < D; ++k) {
            acc += xs[wid][k] * Ws[k * D + lane];
        }
        support[(size_t)row * D + lane] = acc;
    }
}

// ===========================================================================
// Bucket histogram (LDS-staged), scan, and binned scatter
// ===========================================================================
__global__ __launch_bounds__(256) void zero_kernel(int* __restrict__ p, int n) {
    int i = blockIdx.x * 256 + threadIdx.x;
    int stride = gridDim.x * 256;
    for (; i < n; i += stride) p[i] = 0;
}

__global__ __launch_bounds__(256) void bucket_hist_kernel(const int* __restrict__ rows,
                                                          int ne, int* __restrict__ gcnt,
                                                          int nb) {
    __shared__ int lcnt[NBMAX];
    for (int i = threadIdx.x; i < nb; i += 256) lcnt[i] = 0;
    __syncthreads();
    int i = blockIdx.x * 256 + threadIdx.x;
    int stride = gridDim.x * 256;
    for (; i < ne; i += stride) atomicAdd(&lcnt[rows[i] >> 7], 1);
    __syncthreads();
    for (int b = threadIdx.x; b < nb; b += 256) {
        int c = lcnt[b];
        if (c) atomicAdd(&gcnt[b], c);
    }
}

// 1 block: exclusive scan of gcnt[0..nb) -> base (nb+1 entries) and cursor copy
__global__ __launch_bounds__(256) void bucket_scan_kernel(const int* __restrict__ gcnt,
                                                          int nb,
                                                          int* __restrict__ base,
                                                          int* __restrict__ cursor) {
    __shared__ int ts[256];
    const int tid = threadIdx.x;
    int b0 = tid * 4;
    int v[4]; int tsum = 0;
#pragma unroll
    for (int j = 0; j < 4; ++j) {
        int idx = b0 + j;
        v[j] = (idx < nb) ? gcnt[idx] : 0;
        tsum += v[j];
    }
    ts[tid] = tsum;
    __syncthreads();
    for (int off = 1; off < 256; off <<= 1) {
        int t = (tid >= off) ? ts[tid - off] : 0;
        __syncthreads();
        ts[tid] += t;
        __syncthreads();
    }
    int excl = ts[tid] - tsum;
#pragma unroll
    for (int j = 0; j < 4; ++j) {
        int idx = b0 + j;
        if (idx < nb) { base[idx] = excl; cursor[idx] = excl; }
        excl += v[j];
    }
    if (tid == 255) base[nb] = excl;
}

// Each block owns a contiguous edge chunk: local hist -> reserve runs via
// global cursors -> scatter packed (row_local<<17 | col, val). Run lines stay
// in the block's XCD L2 -> ~1 writeback per (block,bucket) line.
__global__ __launch_bounds__(256) void bin_scatter_kernel(const int* __restrict__ rows,
                                                          const int* __restrict__ cols,
                                                          const float* __restrict__ vals,
                                                          int ne,
                                                          int* __restrict__ cursor,
                                                          int nb,
                                                          int2* __restrict__ binned) {
    __shared__ int lcnt[NBMAX];
    __shared__ int lbase[NBMAX];
    const int tid = threadIdx.x;
    const int ce = (ne + gridDim.x - 1) / gridDim.x;
    const int e0 = blockIdx.x * ce;
    const int e1 = min(ne, e0 + ce);

    for (int i = tid; i < nb; i += 256) lcnt[i] = 0;
    __syncthreads();
    for (int e = e0 + tid; e < e1; e += 256) atomicAdd(&lcnt[rows[e] >> 7], 1);
    __syncthreads();
    for (int b = tid; b < nb; b += 256) {
        int c = lcnt[b];
        lbase[b] = c ? atomicAdd(&cursor[b], c) : 0;
    }
    __syncthreads();
    for (int i = tid; i < nb; i += 256) lcnt[i] = 0;   // reuse as local cursor
    __syncthreads();
    for (int e = e0 + tid; e < e1; e += 256) {
        int r = rows[e];
        int b = r >> 7;
        int loc = atomicAdd(&lcnt[b], 1);
        int2 cv;
        cv.x = ((r & (RPB - 1)) << 17) | cols[e];
        cv.y = __float_as_int(vals[e]);
        binned[lbase[b] + loc] = cv;
    }
}

// ===========================================================================
// Accumulate: one block per bucket. 32 KB LDS f32 accumulator (128 rows x 64).
// lane = feature. Wave loads 64 edges coalesced, shfl-broadcasts each,
// gathers support[col] (256 B coalesced), ds_add_f32 into LDS. No global
// atomics. Store + bias coalesced.
// ===========================================================================
__global__ __launch_bounds__(256) void accumulate_kernel(const int* __restrict__ base,
                                                         const int2* __restrict__ binned,
                                                         const float* __restrict__ support,
                                                         const float* __restrict__ bias,
                                                         float* __restrict__ out,
                                                         int n) {
    __shared__ float acc[RPB * D];
    const int tid  = threadIdx.x;
    const int lane = tid & 63;
    const int wid  = tid >> 6;
    const int b    = blockIdx.x;

    for (int i = tid; i < RPB * D; i += 256) acc[i] = 0.0f;
    __syncthreads();

    const int jb = base[b];
    const int je = base[b + 1];

    for (int j0 = jb + wid * 64; j0 < je; j0 += 256) {
        const int m = min(64, je - j0);
        int2 ev = make_int2(0, 0);
        if (lane < m) ev = binned[j0 + lane];
        const int key   = ev.x;
        const int vbits = ev.y;
        if (m == 64) {
#pragma unroll 8
            for (int i = 0; i < 64; ++i) {
                int k = __shfl(key, i);
                float v = __int_as_float(__shfl(vbits, i));
                int rl = k >> 17;
                int c  = k & 0x1FFFF;
                float s = support[(size_t)c * D + lane];
                atomicAdd(&acc[rl * D + lane], v * s);
            }
        } else {
            for (int i = 0; i < m; ++i) {
                int k = __shfl(key, i);
                float v = __int_as_float(__shfl(vbits, i));
                int rl = k >> 17;
                int c  = k & 0x1FFFF;
                float s = support[(size_t)c * D + lane];
                atomicAdd(&acc[rl * D + lane], v * s);
            }
        }
    }
    __syncthreads();

    const float bl = bias[lane];
    const int row0 = b * RPB;
    for (int i = wid; i < RPB; i += 4) {
        int r = row0 + i;
        if (r < n) out[(size_t)r * D + lane] = acc[i * D + lane] + bl;
    }
}

// ===========================================================================
// Fallback (R1, verified): bias-init + atomic scatter
// ===========================================================================
__global__ __launch_bounds__(256) void init_kernel(const float* __restrict__ bias,
                                                   float* __restrict__ out, int total4) {
    int i = blockIdx.x * 256 + threadIdx.x;
    int stride = gridDim.x * 256;
    for (; i < total4; i += stride) {
        int base4 = (i * 4) & (D - 1);
        float4 bv;
        bv.x = bias[base4 + 0]; bv.y = bias[base4 + 1];
        bv.z = bias[base4 + 2]; bv.w = bias[base4 + 3];
        reinterpret_cast<float4*>(out)[i] = bv;
    }
}

__global__ __launch_bounds__(256) void scatter_kernel(const int* __restrict__ rows,
                                                      const int* __restrict__ cols,
                                                      const float* __restrict__ vals,
                                                      const float* __restrict__ support,
                                                      float* __restrict__ out, int ne) {
    const int wid  = blockIdx.x * 4 + (threadIdx.x >> 6);
    const int lane = threadIdx.x & 63;
    const int nw = gridDim.x * 4;
    for (int e = wid; e < ne; e += nw) {
        const int r = rows[e];
        const int c = cols[e];
        const float v = vals[e];
        unsafeAtomicAdd(&out[(size_t)r * D + lane], v * support[(size_t)c * D + lane]);
    }
}

extern "C" void kernel_launch(void* const* d_in, const int* in_sizes, int n_in,
                              void* d_out, int out_size, void* d_ws, size_t ws_size,
                              hipStream_t stream) {
    const float* x         = (const float*)d_in[0];
    const int*   edge_rows = (const int*)d_in[1];
    const int*   edge_cols = (const int*)d_in[2];
    const float* edge_vals = (const float*)d_in[3];
    const float* w_own     = (const float*)d_in[4];
    const float* w_nbr     = (const float*)d_in[5];
    const float* w_temp    = (const float*)d_in[6];
    const float* bias      = (const float*)d_in[7];

    float* out = (float*)d_out;
    const int n_nodes = in_sizes[0] / D;
    const int n_edges = in_sizes[1];
    const int nb = (n_nodes + RPB - 1) / RPB;

    // ---- workspace layout ----
    char* ws = (char*)d_ws;
    size_t off = 0;
    auto take = [&](size_t bytes) -> char* {
        char* p = ws + off;
        off = (off + bytes + 15) & ~(size_t)15;
        return p;
    };
    float* support = (float*)take((size_t)n_nodes * D * sizeof(float));
    int*   gcnt    = (int*)  take((size_t)nb * sizeof(int));
    int*   base    = (int*)  take((size_t)(nb + 1) * sizeof(int));
    int*   cursor  = (int*)  take((size_t)nb * sizeof(int));
    int2*  binned  = (int2*) take((size_t)n_edges * sizeof(int2));
    const bool binned_fits = (off <= ws_size) && (nb <= NBMAX) && (n_nodes <= (1 << 17));

    // support = x @ (W_own + W_nbr + W_temp)
    gemm_kernel<<<1024, 256, 0, stream>>>(x, w_own, w_nbr, w_temp, support, n_nodes);

    if (binned_fits) {
        zero_kernel<<<4, 256, 0, stream>>>(gcnt, nb);
        bucket_hist_kernel<<<512, 256, 0, stream>>>(edge_rows, n_edges, gcnt, nb);
        bucket_scan_kernel<<<1, 256, 0, stream>>>(gcnt, nb, base, cursor);
        bin_scatter_kernel<<<512, 256, 0, stream>>>(edge_rows, edge_cols, edge_vals,
                                                    n_edges, cursor, nb, binned);
        accumulate_kernel<<<nb, 256, 0, stream>>>(base, binned, support, bias, out, n_nodes);
    } else {
        int total4 = (n_nodes * D) / 4;
        int blocks = (total4 + 255) / 256; if (blocks > 2048) blocks = 2048;
        init_kernel<<<blocks, 256, 0, stream>>>(bias, out, total4);
        scatter_kernel<<<2048, 256, 0, stream>>>(edge_rows, edge_cols, edge_vals,
                                                 support, out, n_edges);
    }
}

// Round 4
// 164.205 us; speedup vs baseline: 4.8739x; 4.8739x over previous
//
#include <hip/hip_runtime.h>
#include <hip/hip_bf16.h>

#define D 64
#define RPB 128          // rows per bucket (row_local fits in 7 bits)
#define NBMAX 1024       // max buckets; needs n_nodes <= 131072 (17-bit col)

// ===========================================================================
// support = x @ (W0+W1+W2), stored as bf16 (halves gather traffic + ws size)
// ===========================================================================
__global__ __launch_bounds__(256) void gemm_kernel(const float* __restrict__ x,
                                                   const float* __restrict__ w0,
                                                   const float* __restrict__ w1,
                                                   const float* __restrict__ w2,
                                                   __hip_bfloat16* __restrict__ support,
                                                   int n) {
    __shared__ float Ws[D * D];
    __shared__ float xs[4][D];

    for (int i = threadIdx.x; i < D * D; i += 256)
        Ws[i] = w0[i] + w1[i] + w2[i];
    __syncthreads();

    const int wid  = threadIdx.x >> 6;
    const int lane = threadIdx.x & 63;
    int row = blockIdx.x * 4 + wid;
    const int nw = gridDim.x * 4;

    for (; row < n; row += nw) {
        xs[wid][lane] = x[(size_t)row * D + lane];
        float acc = 0.0f;
#pragma unroll
        for (int k = 0; k < D; ++k) {
            acc += xs[wid][k] * Ws[k * D + lane];
        }
        support[(size_t)row * D + lane] = __float2bfloat16(acc);
    }
}

// f32-support variant for the fallback path
__global__ __launch_bounds__(256) void gemm_f32_kernel(const float* __restrict__ x,
                                                       const float* __restrict__ w0,
                                                       const float* __restrict__ w1,
                                                       const float* __restrict__ w2,
                                                       float* __restrict__ support,
                                                       int n) {
    __shared__ float Ws[D * D];
    __shared__ float xs[4][D];
    for (int i = threadIdx.x; i < D * D; i += 256)
        Ws[i] = w0[i] + w1[i] + w2[i];
    __syncthreads();
    const int wid  = threadIdx.x >> 6;
    const int lane = threadIdx.x & 63;
    int row = blockIdx.x * 4 + wid;
    const int nw = gridDim.x * 4;
    for (; row < n; row += nw) {
        xs[wid][lane] = x[(size_t)row * D + lane];
        float acc = 0.0f;
#pragma unroll
        for (int k = 0; k < D; ++k) acc += xs[wid][k] * Ws[k * D + lane];
        support[(size_t)row * D + lane] = acc;
    }
}

// ===========================================================================
// Coarse binning: hist -> scan -> partition scatter (grouped by 128-row bucket)
// ===========================================================================
__global__ __launch_bounds__(256) void zero_kernel(int* __restrict__ p, int n) {
    int i = blockIdx.x * 256 + threadIdx.x;
    int stride = gridDim.x * 256;
    for (; i < n; i += stride) p[i] = 0;
}

__global__ __launch_bounds__(256) void bucket_hist_kernel(const int* __restrict__ rows,
                                                          int ne, int* __restrict__ gcnt,
                                                          int nb) {
    __shared__ int lcnt[NBMAX];
    for (int i = threadIdx.x; i < nb; i += 256) lcnt[i] = 0;
    __syncthreads();
    int i = blockIdx.x * 256 + threadIdx.x;
    int stride = gridDim.x * 256;
    for (; i < ne; i += stride) atomicAdd(&lcnt[rows[i] >> 7], 1);
    __syncthreads();
    for (int b = threadIdx.x; b < nb; b += 256) {
        int c = lcnt[b];
        if (c) atomicAdd(&gcnt[b], c);
    }
}

// 1 block: exclusive scan of gcnt -> base[nb+1], cursor copy; rowptr[n] = total
__global__ __launch_bounds__(256) void bucket_scan_kernel(const int* __restrict__ gcnt,
                                                          int nb,
                                                          int* __restrict__ base,
                                                          int* __restrict__ cursor,
                                                          int* __restrict__ rowptr,
                                                          int n) {
    __shared__ int ts[256];
    const int tid = threadIdx.x;
    int b0 = tid * 4;
    int v[4]; int tsum = 0;
#pragma unroll
    for (int j = 0; j < 4; ++j) {
        int idx = b0 + j;
        v[j] = (idx < nb) ? gcnt[idx] : 0;
        tsum += v[j];
    }
    ts[tid] = tsum;
    __syncthreads();
    for (int off = 1; off < 256; off <<= 1) {
        int t = (tid >= off) ? ts[tid - off] : 0;
        __syncthreads();
        ts[tid] += t;
        __syncthreads();
    }
    int excl = ts[tid] - tsum;
#pragma unroll
    for (int j = 0; j < 4; ++j) {
        int idx = b0 + j;
        if (idx < nb) { base[idx] = excl; cursor[idx] = excl; }
        excl += v[j];
    }
    if (tid == 255) { base[nb] = excl; rowptr[n] = excl; }
}

// Each block: local hist over its edge chunk -> reserve bucket runs -> scatter
// packed (row_local<<17 | col, val). Run lines stay L2-resident per block.
__global__ __launch_bounds__(256) void bin_scatter_kernel(const int* __restrict__ rows,
                                                          const int* __restrict__ cols,
                                                          const float* __restrict__ vals,
                                                          int ne,
                                                          int* __restrict__ cursor,
                                                          int nb,
                                                          int2* __restrict__ binned) {
    __shared__ int lcnt[NBMAX];
    __shared__ int lbase[NBMAX];
    const int tid = threadIdx.x;
    const int ce = (ne + gridDim.x - 1) / gridDim.x;
    const int e0 = blockIdx.x * ce;
    const int e1 = min(ne, e0 + ce);

    for (int i = tid; i < nb; i += 256) lcnt[i] = 0;
    __syncthreads();
    for (int e = e0 + tid; e < e1; e += 256) atomicAdd(&lcnt[rows[e] >> 7], 1);
    __syncthreads();
    for (int b = tid; b < nb; b += 256) {
        int c = lcnt[b];
        lbase[b] = c ? atomicAdd(&cursor[b], c) : 0;
    }
    __syncthreads();
    for (int i = tid; i < nb; i += 256) lcnt[i] = 0;   // reuse as local cursor
    __syncthreads();
    for (int e = e0 + tid; e < e1; e += 256) {
        int r = rows[e];
        int b = r >> 7;
        int loc = atomicAdd(&lcnt[b], 1);
        int2 cv;
        cv.x = ((r & (RPB - 1)) << 17) | cols[e];
        cv.y = __float_as_int(vals[e]);
        binned[lbase[b] + loc] = cv;
    }
}

// ===========================================================================
// local_csr: one block per bucket. LDS 128-row hist + scan, write rowptr,
// then scatter binned -> csr sorted by row. All writes land in this bucket's
// contiguous ~16KB window -> L2-resident until complete (no 100MB writeback).
// ===========================================================================
__global__ __launch_bounds__(256) void local_csr_kernel(const int* __restrict__ base,
                                                        const int2* __restrict__ binned,
                                                        int* __restrict__ rowptr,
                                                        int2* __restrict__ csr,
                                                        int n) {
    __shared__ int lh[RPB];   // hist, then global write-cursor per local row
    __shared__ int lp[RPB];   // inclusive prefix
    const int tid = threadIdx.x;
    const int b = blockIdx.x;
    const int jb = base[b], je = base[b + 1];

    for (int i = tid; i < RPB; i += 256) lh[i] = 0;
    __syncthreads();
    for (int j = jb + tid; j < je; j += 256) atomicAdd(&lh[binned[j].x >> 17], 1);
    __syncthreads();
    if (tid < RPB) lp[tid] = lh[tid];
    __syncthreads();
    for (int off = 1; off < RPB; off <<= 1) {
        int t = (tid < RPB && tid >= off) ? lp[tid - off] : 0;
        __syncthreads();
        if (tid < RPB) lp[tid] += t;
        __syncthreads();
    }
    if (tid < RPB) {
        int excl = lp[tid] - lh[tid];
        int start = jb + excl;
        lh[tid] = start;                 // becomes cursor
        int r = b * RPB + tid;
        if (r < n) rowptr[r] = start;
    }
    __syncthreads();
    for (int j = jb + tid; j < je; j += 256) {
        int2 e = binned[j];
        int rl = e.x >> 17;
        int pos = atomicAdd(&lh[rl], 1);
        int2 o; o.x = e.x & 0x1FFFF; o.y = e.y;
        csr[pos] = o;
    }
}

// ===========================================================================
// Pull: out[r] = bias + sum_j val[j] * support[col[j]]  — register accumulate,
// bf16 gathers (128B/edge), 4-way unroll for latency overlap. No atomics.
// ===========================================================================
__global__ __launch_bounds__(256) void pull_kernel(const int* __restrict__ rowptr,
                                                   const int2* __restrict__ csr,
                                                   const __hip_bfloat16* __restrict__ sup,
                                                   const float* __restrict__ bias,
                                                   float* __restrict__ out, int n) {
    const int lane = threadIdx.x & 63;
    int w = blockIdx.x * 4 + (threadIdx.x >> 6);
    const int nw = gridDim.x * 4;
    const float bl = bias[lane];
    for (int r = w; r < n; r += nw) {
        int jb = rowptr[r], je = rowptr[r + 1];
        float a0 = 0.f, a1 = 0.f, a2 = 0.f, a3 = 0.f;
        int j = jb;
        for (; j + 3 < je; j += 4) {
            int2 e0 = csr[j], e1 = csr[j + 1], e2 = csr[j + 2], e3 = csr[j + 3];
            a0 += __int_as_float(e0.y) * __bfloat162float(sup[(size_t)e0.x * D + lane]);
            a1 += __int_as_float(e1.y) * __bfloat162float(sup[(size_t)e1.x * D + lane]);
            a2 += __int_as_float(e2.y) * __bfloat162float(sup[(size_t)e2.x * D + lane]);
            a3 += __int_as_float(e3.y) * __bfloat162float(sup[(size_t)e3.x * D + lane]);
        }
        for (; j < je; ++j) {
            int2 e = csr[j];
            a0 += __int_as_float(e.y) * __bfloat162float(sup[(size_t)e.x * D + lane]);
        }
        out[(size_t)r * D + lane] = (a0 + a1) + (a2 + a3) + bl;
    }
}

// ===========================================================================
// Fallback (R1, verified): bias-init + atomic scatter (f32 support)
// ===========================================================================
__global__ __launch_bounds__(256) void init_kernel(const float* __restrict__ bias,
                                                   float* __restrict__ out, int total4) {
    int i = blockIdx.x * 256 + threadIdx.x;
    int stride = gridDim.x * 256;
    for (; i < total4; i += stride) {
        int base4 = (i * 4) & (D - 1);
        float4 bv;
        bv.x = bias[base4 + 0]; bv.y = bias[base4 + 1];
        bv.z = bias[base4 + 2]; bv.w = bias[base4 + 3];
        reinterpret_cast<float4*>(out)[i] = bv;
    }
}

__global__ __launch_bounds__(256) void scatter_kernel(const int* __restrict__ rows,
                                                      const int* __restrict__ cols,
                                                      const float* __restrict__ vals,
                                                      const float* __restrict__ support,
                                                      float* __restrict__ out, int ne) {
    const int wid  = blockIdx.x * 4 + (threadIdx.x >> 6);
    const int lane = threadIdx.x & 63;
    const int nw = gridDim.x * 4;
    for (int e = wid; e < ne; e += nw) {
        const int r = rows[e];
        const int c = cols[e];
        const float v = vals[e];
        unsafeAtomicAdd(&out[(size_t)r * D + lane], v * support[(size_t)c * D + lane]);
    }
}

extern "C" void kernel_launch(void* const* d_in, const int* in_sizes, int n_in,
                              void* d_out, int out_size, void* d_ws, size_t ws_size,
                              hipStream_t stream) {
    const float* x         = (const float*)d_in[0];
    const int*   edge_rows = (const int*)d_in[1];
    const int*   edge_cols = (const int*)d_in[2];
    const float* edge_vals = (const float*)d_in[3];
    const float* w_own     = (const float*)d_in[4];
    const float* w_nbr     = (const float*)d_in[5];
    const float* w_temp    = (const float*)d_in[6];
    const float* bias      = (const float*)d_in[7];

    float* out = (float*)d_out;
    const int n_nodes = in_sizes[0] / D;
    const int n_edges = in_sizes[1];
    const int nb = (n_nodes + RPB - 1) / RPB;

    // ---- workspace layout (bf16 support keeps total under R2's proven size) ----
    char* ws = (char*)d_ws;
    size_t off = 0;
    auto take = [&](size_t bytes) -> char* {
        char* p = ws + off;
        off = (off + bytes + 15) & ~(size_t)15;
        return p;
    };
    __hip_bfloat16* support = (__hip_bfloat16*)take((size_t)n_nodes * D * sizeof(__hip_bfloat16));
    int2* binned = (int2*)take((size_t)n_edges * sizeof(int2));
    int2* csr    = (int2*)take((size_t)n_edges * sizeof(int2));
    int*  rowptr = (int*) take((size_t)(n_nodes + 1) * sizeof(int));
    int*  gcnt   = (int*) take((size_t)nb * sizeof(int));
    int*  base   = (int*) take((size_t)(nb + 1) * sizeof(int));
    int*  cursor = (int*) take((size_t)nb * sizeof(int));
    const bool full_fits = (off <= ws_size) && (nb <= NBMAX) && (n_nodes <= (1 << 17));

    if (full_fits) {
        gemm_kernel<<<1024, 256, 0, stream>>>(x, w_own, w_nbr, w_temp, support, n_nodes);
        zero_kernel<<<4, 256, 0, stream>>>(gcnt, nb);
        bucket_hist_kernel<<<512, 256, 0, stream>>>(edge_rows, n_edges, gcnt, nb);
        bucket_scan_kernel<<<1, 256, 0, stream>>>(gcnt, nb, base, cursor, rowptr, n_nodes);
        bin_scatter_kernel<<<512, 256, 0, stream>>>(edge_rows, edge_cols, edge_vals,
                                                    n_edges, cursor, nb, binned);
        local_csr_kernel<<<nb, 256, 0, stream>>>(base, binned, rowptr, csr, n_nodes);
        pull_kernel<<<2048, 256, 0, stream>>>(rowptr, csr, support, bias, out, n_nodes);
    } else {
        // R1 fallback: f32 support + atomic scatter
        float* support_f = (float*)d_ws;
        gemm_f32_kernel<<<1024, 256, 0, stream>>>(x, w_own, w_nbr, w_temp, support_f, n_nodes);
        int total4 = (n_nodes * D) / 4;
        int blocks = (total4 + 255) / 256; if (blocks > 2048) blocks = 2048;
        init_kernel<<<blocks, 256, 0, stream>>>(bias, out, total4);
        scatter_kernel<<<2048, 256, 0, stream>>>(edge_rows, edge_cols, edge_vals,
                                                 support_f, out, n_edges);
    }
}